// Round 6
// baseline (137.876 us; speedup 1.0000x reference)
//
#include <hip/hip_runtime.h>
#include <math.h>

// Hit-miss transform: out[i][j] = min_{di,dj}(x[i+di][j+dj] - Khit[di][dj])
//                               - max_{di,dj}(x[i+di][j+dj] - Kmiss[di][dj])
// H=W=4096 fp32 input, 5x5 kernels, output 4092x4092 fp32.
//
// R9: pixel-pair packed subtracts, delivery vehicle #3. Evidence so far:
//  - packing works (R6: VALU busy 30->20us) but asm "s"-pairs killed the
//    schedule; R7's spill came from ARRAYS of vector type + launch_bounds
//    reg cap (WRITE 425MB scratch), not from the pk pattern.
//  - scalar engine is pinned at ~41.4us/~142 instr/px regardless of source
//    shape (R4~R5~R8); width scaling regressed (R8: pressure-induced +36/px).
// This round: NAMED v2f (ext_vector) scalars only — no vector arrays, no
// launch-bounds cap, no asm subs. fadd <2 x float> selects V_PK_ADD_F32 on
// gfx90a+ with SGPR-splat folded via op_sel. Even input pairs free from
// aligned dwordx4; odd pairs from dual-alignment loads (+4B/+20B, same
// cache lines -> no HBM delta, no shuffle movs). Weights pre-negated:
// v+(-w) IEEE-identical to v-w. Reduction trees unchanged from R4 (scalar
// min3/max3 on register halves). Core 75 -> 54 instr/px.
// Grid: 4 x 1023 = 4092 blocks (packs >=99.6% at 4 blk/CU, exactly at 8).

constexpr int KS  = 5;
constexpr int WW  = 4096;
constexpr int HO  = 4092;
constexpr int WO  = 4092;
constexpr int CG  = WO / 4;   // 1023 column groups
constexpr int RPT = 4;        // output rows per thread (4092 = 4*1023)

typedef float v2f  __attribute__((ext_vector_type(2)));
typedef float f4a4 __attribute__((ext_vector_type(4), aligned(4)));
typedef float f2a4 __attribute__((ext_vector_type(2), aligned(4)));

__device__ __forceinline__ v2f splat(float s) { v2f r; r.x = s; r.y = s; return r; }

__device__ __forceinline__ float min3f(float a, float b, float c) {
    float d;
    asm("v_min3_f32 %0, %1, %2, %3" : "=v"(d) : "v"(a), "v"(b), "v"(c));
    return d;
}
__device__ __forceinline__ float max3f(float a, float b, float c) {
    float d;
    asm("v_max3_f32 %0, %1, %2, %3" : "=v"(d) : "v"(a), "v"(b), "v"(c));
    return d;
}

__device__ __forceinline__ float red5_min(float t0, float t1, float t2, float t3, float t4) {
    return min3f(min3f(t0, t1, t2), t3, t4);
}
__device__ __forceinline__ float red5_max(float t0, float t1, float t2, float t3, float t4) {
    return max3f(max3f(t0, t1, t2), t3, t4);
}
__device__ __forceinline__ float red5acc_min(float acc, float t0, float t1, float t2, float t3, float t4) {
    return fminf(min3f(t0, t1, t2), min3f(t3, t4, acc));
}
__device__ __forceinline__ float red5acc_max(float acc, float t0, float t1, float t2, float t3, float t4) {
    return fmaxf(max3f(t0, t1, t2), max3f(t3, t4, acc));
}

__global__ __launch_bounds__(256) void hitmiss_kernel(
    const float* __restrict__ x,
    const float* __restrict__ kh,
    const float* __restrict__ km,
    float* __restrict__ out)
{
    const int cg = blockIdx.x * blockDim.x + threadIdx.x;  // column group
    if (cg >= CG) return;
    const int j0 = cg * 4;
    const int r0 = blockIdx.y * RPT;

    // Pre-negated weights, uniform -> SGPRs. v + nw == v - w exactly.
    float nh[KS * KS], nm[KS * KS];
#pragma unroll
    for (int k = 0; k < KS * KS; ++k) {
        nh[k] = -kh[k];
        nm[k] = -km[k];
    }

    const float* base = x + (size_t)r0 * WW + j0;

    float mn[RPT][4], mx[RPT][4];   // scalar accumulators (proven resident)

#pragma unroll
    for (int i = 0; i < RPT + 4; ++i) {
        const float* rp = base + (size_t)i * WW;
        // Even pairs from two 16B-aligned dwordx4; odd pairs from
        // dual-alignment loads at +4B / +20B (dword-aligned, same lines).
        float4 a = *reinterpret_cast<const float4*>(rp);       // e0..e3
        float4 b = *reinterpret_cast<const float4*>(rp + 4);   // e4..e7
        f4a4   c = *reinterpret_cast<const f4a4 *>(rp + 1);    // e1..e4
        f2a4   d = *reinterpret_cast<const f2a4 *>(rp + 5);    // e5,e6

        v2f E0; E0.x = a.x; E0.y = a.y;   // (e0,e1)
        v2f E1; E1.x = a.z; E1.y = a.w;   // (e2,e3)
        v2f E2; E2.x = b.x; E2.y = b.y;   // (e4,e5)
        v2f E3; E3.x = b.z; E3.y = b.w;   // (e6,e7)
        v2f O0; O0.x = c.x; O0.y = c.y;   // (e1,e2)
        v2f O1; O1.x = c.z; O1.y = c.w;   // (e3,e4)
        v2f O2; O2.x = d.x; O2.y = d.y;   // (e5,e6)

#pragma unroll
        for (int o = 0; o < RPT; ++o) {
            const int di = i - o;              // static after unroll
            if (di < 0 || di > KS - 1) continue;
            const int kb = di * KS;

            // Hit side: pixel pair (0,1) uses pairs E0,O0,E1,O1,E2;
            //           pixel pair (2,3) uses pairs E1,O1,E2,O2,E3.
            const v2f h01_0 = E0 + splat(nh[kb + 0]);
            const v2f h01_1 = O0 + splat(nh[kb + 1]);
            const v2f h01_2 = E1 + splat(nh[kb + 2]);
            const v2f h01_3 = O1 + splat(nh[kb + 3]);
            const v2f h01_4 = E2 + splat(nh[kb + 4]);
            const v2f h23_0 = E1 + splat(nh[kb + 0]);
            const v2f h23_1 = O1 + splat(nh[kb + 1]);
            const v2f h23_2 = E2 + splat(nh[kb + 2]);
            const v2f h23_3 = O2 + splat(nh[kb + 3]);
            const v2f h23_4 = E3 + splat(nh[kb + 4]);
            // Miss side:
            const v2f m01_0 = E0 + splat(nm[kb + 0]);
            const v2f m01_1 = O0 + splat(nm[kb + 1]);
            const v2f m01_2 = E1 + splat(nm[kb + 2]);
            const v2f m01_3 = O1 + splat(nm[kb + 3]);
            const v2f m01_4 = E2 + splat(nm[kb + 4]);
            const v2f m23_0 = E1 + splat(nm[kb + 0]);
            const v2f m23_1 = O1 + splat(nm[kb + 1]);
            const v2f m23_2 = E2 + splat(nm[kb + 2]);
            const v2f m23_3 = O2 + splat(nm[kb + 3]);
            const v2f m23_4 = E3 + splat(nm[kb + 4]);

            if (di == 0) {
                mn[o][0] = red5_min(h01_0.x, h01_1.x, h01_2.x, h01_3.x, h01_4.x);
                mn[o][1] = red5_min(h01_0.y, h01_1.y, h01_2.y, h01_3.y, h01_4.y);
                mn[o][2] = red5_min(h23_0.x, h23_1.x, h23_2.x, h23_3.x, h23_4.x);
                mn[o][3] = red5_min(h23_0.y, h23_1.y, h23_2.y, h23_3.y, h23_4.y);
                mx[o][0] = red5_max(m01_0.x, m01_1.x, m01_2.x, m01_3.x, m01_4.x);
                mx[o][1] = red5_max(m01_0.y, m01_1.y, m01_2.y, m01_3.y, m01_4.y);
                mx[o][2] = red5_max(m23_0.x, m23_1.x, m23_2.x, m23_3.x, m23_4.x);
                mx[o][3] = red5_max(m23_0.y, m23_1.y, m23_2.y, m23_3.y, m23_4.y);
            } else {
                mn[o][0] = red5acc_min(mn[o][0], h01_0.x, h01_1.x, h01_2.x, h01_3.x, h01_4.x);
                mn[o][1] = red5acc_min(mn[o][1], h01_0.y, h01_1.y, h01_2.y, h01_3.y, h01_4.y);
                mn[o][2] = red5acc_min(mn[o][2], h23_0.x, h23_1.x, h23_2.x, h23_3.x, h23_4.x);
                mn[o][3] = red5acc_min(mn[o][3], h23_0.y, h23_1.y, h23_2.y, h23_3.y, h23_4.y);
                mx[o][0] = red5acc_max(mx[o][0], m01_0.x, m01_1.x, m01_2.x, m01_3.x, m01_4.x);
                mx[o][1] = red5acc_max(mx[o][1], m01_0.y, m01_1.y, m01_2.y, m01_3.y, m01_4.y);
                mx[o][2] = red5acc_max(mx[o][2], m23_0.x, m23_1.x, m23_2.x, m23_3.x, m23_4.x);
                mx[o][3] = red5acc_max(mx[o][3], m23_0.y, m23_1.y, m23_2.y, m23_3.y, m23_4.y);
            }
        }

        // Output row o = i-4 complete; store and free its accumulators.
        if (i >= KS - 1) {
            const int o = i - (KS - 1);
            float4 oo;
            oo.x = mn[o][0] - mx[o][0];
            oo.y = mn[o][1] - mx[o][1];
            oo.z = mn[o][2] - mx[o][2];
            oo.w = mn[o][3] - mx[o][3];
            *reinterpret_cast<float4*>(out + (size_t)(r0 + o) * WO + j0) = oo;
        }
    }
}

extern "C" void kernel_launch(void* const* d_in, const int* in_sizes, int n_in,
                              void* d_out, int out_size, void* d_ws, size_t ws_size,
                              hipStream_t stream) {
    const float* x  = (const float*)d_in[0];
    const float* kh = (const float*)d_in[1];
    const float* km = (const float*)d_in[2];
    float* out = (float*)d_out;

    dim3 block(256, 1, 1);
    dim3 grid((CG + 255) / 256, HO / RPT, 1);  // 4 x 1023 = 4092 blocks
    hipLaunchKernelGGL(hitmiss_kernel, grid, block, 0, stream, x, kh, km, out);
}

// Round 7
// 129.493 us; speedup vs baseline: 1.0647x; 1.0647x over previous
//
#include <hip/hip_runtime.h>
#include <math.h>

// Hit-miss transform: out[i][j] = min_{di,dj}(x[i+di][j+dj] - Khit[di][dj])
//                               - max_{di,dj}(x[i+di][j+dj] - Kmiss[di][dj])
// H=W=4096 fp32 input, 5x5 kernels, output 4092x4092 fp32.
//
// R10: un-strangle the register allocator. Evidence across R4-R9: every
// compiler-liked variant sits at 32-52 VGPRs and ~142 VALU instr/px vs 75
// core — the allocator targets max occupancy, refuses the ~56-reg streaming
// state (8 row regs + 32 acc), and pays ~67/px in rematerialized loads +
// v_mov shuffling. pk-f32 packing was tried 3 ways (asm / vector-array /
// named v2f): only asm cut busy (30->20us) but wrecked the schedule; C forms
// never selected pk. Dropped. This round keeps R5's proven bit-exact scalar
// streaming engine (41.7us) and changes ONE thing: __launch_bounds__(256,4)
// -> min 4 waves/EU -> VGPR budget 128, letting the streaming structure
// actually live in registers (loads once per row, acc resident, no remat).
// Occupancy: 4 blocks/CU = 1024 resident; grid 4092 = 4x1023 -> 4.00 rounds
// at >=99.6% fill. Tripwires: VGPR stuck <=40 => hint ignored, structural
// ceiling; FETCH/WRITE balloon => spill.

constexpr int KS  = 5;
constexpr int WW  = 4096;
constexpr int HO  = 4092;
constexpr int WO  = 4092;
constexpr int CG  = WO / 4;   // 1023 column groups
constexpr int RPT = 4;        // output rows per thread (4092 = 4*1023)

__device__ __forceinline__ float min3f(float a, float b, float c) {
    float d;
    asm("v_min3_f32 %0, %1, %2, %3" : "=v"(d) : "v"(a), "v"(b), "v"(c));
    return d;
}
__device__ __forceinline__ float max3f(float a, float b, float c) {
    float d;
    asm("v_max3_f32 %0, %1, %2, %3" : "=v"(d) : "v"(a), "v"(b), "v"(c));
    return d;
}

__device__ __forceinline__ float red5_min(float t0, float t1, float t2, float t3, float t4) {
    return min3f(min3f(t0, t1, t2), t3, t4);
}
__device__ __forceinline__ float red5_max(float t0, float t1, float t2, float t3, float t4) {
    return max3f(max3f(t0, t1, t2), t3, t4);
}
__device__ __forceinline__ float red5acc_min(float acc, float t0, float t1, float t2, float t3, float t4) {
    return fminf(min3f(t0, t1, t2), min3f(t3, t4, acc));
}
__device__ __forceinline__ float red5acc_max(float acc, float t0, float t1, float t2, float t3, float t4) {
    return fmaxf(max3f(t0, t1, t2), max3f(t3, t4, acc));
}

__global__ __launch_bounds__(256, 4) void hitmiss_kernel(
    const float* __restrict__ x,
    const float* __restrict__ kh,
    const float* __restrict__ km,
    float* __restrict__ out)
{
    const int cg = blockIdx.x * blockDim.x + threadIdx.x;  // column group
    if (cg >= CG) return;
    const int j0 = cg * 4;
    const int r0 = blockIdx.y * RPT;

    // Kernel weights: uniform addresses -> scalar (SGPR) loads.
    float wh[KS * KS], wm[KS * KS];
#pragma unroll
    for (int k = 0; k < KS * KS; ++k) {
        wh[k] = kh[k];
        wm[k] = km[k];
    }

    const float* base = x + (size_t)r0 * WW + j0;

    // Accumulators for RPT output rows x 4 pixels — with the 128-VGPR budget
    // these stay register-resident alongside the row values.
    float mn[RPT][4], mx[RPT][4];

#pragma unroll
    for (int i = 0; i < RPT + 4; ++i) {
        // Load input row r0+i exactly once (2x dwordx4), consume, discard.
        float4 a = *reinterpret_cast<const float4*>(base + (size_t)i * WW);
        float4 b = *reinterpret_cast<const float4*>(base + (size_t)i * WW + 4);
        const float v[8] = {a.x, a.y, a.z, a.w, b.x, b.y, b.z, b.w};

#pragma unroll
        for (int o = 0; o < RPT; ++o) {
            const int di = i - o;              // static after unroll
            if (di < 0 || di > KS - 1) continue;
            const int kb = di * KS;
            const float h0 = wh[kb + 0], h1 = wh[kb + 1], h2 = wh[kb + 2],
                        h3 = wh[kb + 3], h4 = wh[kb + 4];
            const float m0 = wm[kb + 0], m1 = wm[kb + 1], m2 = wm[kb + 2],
                        m3 = wm[kb + 3], m4 = wm[kb + 4];

#pragma unroll
            for (int p = 0; p < 4; ++p) {
                const float t0 = v[p + 0] - h0;
                const float t1 = v[p + 1] - h1;
                const float t2 = v[p + 2] - h2;
                const float t3 = v[p + 3] - h3;
                const float t4 = v[p + 4] - h4;
                const float u0 = v[p + 0] - m0;
                const float u1 = v[p + 1] - m1;
                const float u2 = v[p + 2] - m2;
                const float u3 = v[p + 3] - m3;
                const float u4 = v[p + 4] - m4;
                if (di == 0) {
                    mn[o][p] = red5_min(t0, t1, t2, t3, t4);
                    mx[o][p] = red5_max(u0, u1, u2, u3, u4);
                } else {
                    mn[o][p] = red5acc_min(mn[o][p], t0, t1, t2, t3, t4);
                    mx[o][p] = red5acc_max(mx[o][p], u0, u1, u2, u3, u4);
                }
            }
        }

        // Output row o = i-4 complete; store and free its accumulators.
        if (i >= KS - 1) {
            const int o = i - (KS - 1);
            float4 oo;
            oo.x = mn[o][0] - mx[o][0];
            oo.y = mn[o][1] - mx[o][1];
            oo.z = mn[o][2] - mx[o][2];
            oo.w = mn[o][3] - mx[o][3];
            *reinterpret_cast<float4*>(out + (size_t)(r0 + o) * WO + j0) = oo;
        }
    }
}

extern "C" void kernel_launch(void* const* d_in, const int* in_sizes, int n_in,
                              void* d_out, int out_size, void* d_ws, size_t ws_size,
                              hipStream_t stream) {
    const float* x  = (const float*)d_in[0];
    const float* kh = (const float*)d_in[1];
    const float* km = (const float*)d_in[2];
    float* out = (float*)d_out;

    dim3 block(256, 1, 1);
    dim3 grid((CG + 255) / 256, HO / RPT, 1);  // 4 x 1023 = 4092 blocks
    hipLaunchKernelGGL(hitmiss_kernel, grid, block, 0, stream, x, kh, km, out);
}